// Round 4
// baseline (902.065 us; speedup 1.0000x reference)
//
#include <hip/hip_runtime.h>
#include <hip/hip_bf16.h>

typedef __bf16 bf16;
typedef __bf16 bf16x8 __attribute__((ext_vector_type(8)));
typedef __bf16 bf16x4 __attribute__((ext_vector_type(4)));
typedef float  f32x4  __attribute__((ext_vector_type(4)));

#define MFMA16(a, b, c) __builtin_amdgcn_mfma_f32_16x16x32_bf16(a, b, c, 0, 0, 0)

// ---------------------------------------------------------------------------
// Pipelined GEMM: C[M,N] = A[M,K] * B[N,K]^T.  A row stride lda.
// Double-buffered LDS + register prefetch; one barrier per K-iter.
// AF32/BF32: operand f32 in global -> bf16 at LDS-store time.
// EPI 0: bf16 out.  EPI 1: f32 out = acc + Res.  EPI 2: f32 out.
// SK=2: in-block split-K.  512 threads; wave-group g handles K-half g with
// its own LDS buffers; partials combined via LDS (aliases As) at the end.
// ---------------------------------------------------------------------------
template <int EPI, int AF32, int BF32, int TM, int TN, int SK = 1>
__global__ __launch_bounds__(256 * SK) void gemm_bt(
    const void* __restrict__ Av, const void* __restrict__ Bv,
    const float* __restrict__ Res, void* __restrict__ Out,
    int Ntot, int Ktot, int lda)
{
    constexpr int PA = TM / 64, PB = TN / 64;
    constexpr int WN = (TN == 128) ? ((TM == 128) ? 2 : 4) : 2;
    constexpr int WM = 4 / WN;
    constexpr int I = TM / (WM * 16), J = TN / (WN * 16);
    __shared__ __align__(16) bf16 As[2][SK][TM][40];
    __shared__ __align__(16) bf16 Bs[2][SK][TN][40];
    static_assert(SK == 1 || sizeof(As) >= TM * TN * 4, "combine buffer fits in As");
    const int tid  = threadIdx.x;
    const int grp  = (SK > 1) ? (tid >> 8) : 0;
    const int t8   = tid & 255;
    const int wave = t8 >> 6, lane = tid & 63;
    const int quad = lane >> 4, l16 = lane & 15;
    const int wm = wave / WN, wn = wave % WN;
    const int rowW = wm * (TM / WM), colW = wn * (TN / WN);
    const int rowBase = blockIdx.y * TM, colBase = blockIdx.x * TN;

    f32x4 acc[I][J];
    const f32x4 z4 = {0.f, 0.f, 0.f, 0.f};
#pragma unroll
    for (int i = 0; i < I; i++)
#pragma unroll
        for (int j = 0; j < J; j++) acc[i][j] = z4;

    float4 rAf[PA][2]; bf16x8 rAb[PA];
    float4 rBf[PB][2]; bf16x8 rBb[PB];

    auto loadTile = [&](int kt) {   // kt: absolute K offset
#pragma unroll
        for (int p = 0; p < PA; p++) {
            int ch = p * 256 + t8, r = ch >> 2, c8 = (ch & 3) << 3;
            if (AF32) {
                const float* s = (const float*)Av + (size_t)(rowBase + r) * lda + kt + c8;
                rAf[p][0] = *(const float4*)s; rAf[p][1] = *(const float4*)(s + 4);
            } else {
                rAb[p] = *(const bf16x8*)((const bf16*)Av + (size_t)(rowBase + r) * lda + kt + c8);
            }
        }
#pragma unroll
        for (int p = 0; p < PB; p++) {
            int ch = p * 256 + t8, r = ch >> 2, c8 = (ch & 3) << 3;
            if (BF32) {
                const float* s = (const float*)Bv + (size_t)(colBase + r) * Ktot + kt + c8;
                rBf[p][0] = *(const float4*)s; rBf[p][1] = *(const float4*)(s + 4);
            } else {
                rBb[p] = *(const bf16x8*)((const bf16*)Bv + (size_t)(colBase + r) * Ktot + kt + c8);
            }
        }
    };
    auto storeTile = [&](int buf) {
#pragma unroll
        for (int p = 0; p < PA; p++) {
            int ch = p * 256 + t8, r = ch >> 2, c8 = (ch & 3) << 3;
            bf16x8 t;
            if (AF32) {
                t[0]=(bf16)rAf[p][0].x; t[1]=(bf16)rAf[p][0].y; t[2]=(bf16)rAf[p][0].z; t[3]=(bf16)rAf[p][0].w;
                t[4]=(bf16)rAf[p][1].x; t[5]=(bf16)rAf[p][1].y; t[6]=(bf16)rAf[p][1].z; t[7]=(bf16)rAf[p][1].w;
            } else t = rAb[p];
            *(bf16x8*)&As[buf][grp][r][c8] = t;
        }
#pragma unroll
        for (int p = 0; p < PB; p++) {
            int ch = p * 256 + t8, r = ch >> 2, c8 = (ch & 3) << 3;
            bf16x8 t;
            if (BF32) {
                t[0]=(bf16)rBf[p][0].x; t[1]=(bf16)rBf[p][0].y; t[2]=(bf16)rBf[p][0].z; t[3]=(bf16)rBf[p][0].w;
                t[4]=(bf16)rBf[p][1].x; t[5]=(bf16)rBf[p][1].y; t[6]=(bf16)rBf[p][1].z; t[7]=(bf16)rBf[p][1].w;
            } else t = rBb[p];
            *(bf16x8*)&Bs[buf][grp][r][c8] = t;
        }
    };

    const int Kgrp  = Ktot / SK;
    const int kbase = grp * Kgrp;
    loadTile(kbase);
    storeTile(0);
    __syncthreads();
    const int nk = Kgrp >> 5;
    for (int k = 0; k < nk; k++) {
        const bool more = (k + 1) < nk;
        if (more) loadTile(kbase + ((k + 1) << 5));
        const int buf = k & 1;
        bf16x8 af[I], bfr[J];
#pragma unroll
        for (int i = 0; i < I; i++)
            af[i] = *(const bf16x8*)&As[buf][grp][rowW + i * 16 + l16][quad * 8];
#pragma unroll
        for (int j = 0; j < J; j++)
            bfr[j] = *(const bf16x8*)&Bs[buf][grp][colW + j * 16 + l16][quad * 8];
#pragma unroll
        for (int i = 0; i < I; i++)
#pragma unroll
            for (int j = 0; j < J; j++)
                acc[i][j] = MFMA16(af[i], bfr[j], acc[i][j]);
        if (more) { storeTile(buf ^ 1); __syncthreads(); }
    }

    // --- SK=2: combine group 1's partial into group 0 via LDS ---
    if (SK == 2) {
        __syncthreads();                       // all main-loop LDS reads done
        float* red = (float*)&As[0][0][0][0];  // TM*TN*4 bytes, fits (assert)
        if (grp == 1) {
#pragma unroll
            for (int i = 0; i < I; i++)
#pragma unroll
                for (int j = 0; j < J; j++)
#pragma unroll
                    for (int r = 0; r < 4; r++)
                        red[(rowW + i * 16 + quad * 4 + r) * TN +
                            (colW + j * 16 + l16)] = acc[i][j][r];
        }
        __syncthreads();
        if (grp != 0) return;
#pragma unroll
        for (int i = 0; i < I; i++)
#pragma unroll
            for (int j = 0; j < J; j++)
#pragma unroll
                for (int r = 0; r < 4; r++)
                    acc[i][j][r] += red[(rowW + i * 16 + quad * 4 + r) * TN +
                                        (colW + j * 16 + l16)];
    }

    // C/D layout: row = quad*4 + r, col = l16 (verified m89/m91)
#pragma unroll
    for (int i = 0; i < I; i++) {
        int row0 = rowBase + rowW + i * 16 + quad * 4;
#pragma unroll
        for (int j = 0; j < J; j++) {
            int col = colBase + colW + j * 16 + l16;
#pragma unroll
            for (int r = 0; r < 4; r++) {
                size_t off = (size_t)(row0 + r) * Ntot + col;
                float v = acc[i][j][r];
                if (EPI == 0)      ((bf16*)Out)[off]  = (bf16)v;
                else if (EPI == 1) ((float*)Out)[off] = v + Res[off];
                else               ((float*)Out)[off] = v;
            }
        }
    }
}

// ---------------------------------------------------------------------------
// Fused Wup GEMM + SwiGLU, in-block split-K (SK=2): 512 threads.
// Wave-group grp handles K-half grp (16 iters instead of 32) with its own
// LDS double-buffer; partials combined via 64 KB LDS f32 buffer (aliases
// Smem).  128row x 64col hg tile per block.
// Smem rows: [0,128) = A tile, [128,256) = B tile.
// ---------------------------------------------------------------------------
__global__ __launch_bounds__(512) void gemm_up_swiglu(
    const bf16* __restrict__ A, const float* __restrict__ B,
    bf16* __restrict__ Out)
{
    __shared__ __align__(16) bf16 Smem[2][2][256][40];   // 80 KB
    const int tid  = threadIdx.x;
    const int grp  = tid >> 8, t8 = tid & 255;
    const int wave = t8 >> 6, lane = tid & 63;
    const int quad = lane >> 4, l16 = lane & 15;
    const int wm = wave >> 1, wn = wave & 1;
    const int rowBase = blockIdx.y * 128, cb = blockIdx.x;

    f32x4 acc[4][4];
    const f32x4 z4 = {0.f, 0.f, 0.f, 0.f};
#pragma unroll
    for (int i = 0; i < 4; i++)
#pragma unroll
        for (int j = 0; j < 4; j++) acc[i][j] = z4;

    bf16x8 rA[2]; float4 rB[2][2];
    auto loadTile = [&](int kt) {   // absolute K offset
#pragma unroll
        for (int p = 0; p < 2; p++) {
            int ch = p * 256 + t8, r = ch >> 2, c8 = (ch & 3) << 3;
            rA[p] = *(const bf16x8*)(A + (size_t)(rowBase + r) * 1024 + kt + c8);
            int brow = (r >> 6) * 2048 + cb * 64 + (r & 63);
            const float* s = B + (size_t)brow * 1024 + kt + c8;
            rB[p][0] = *(const float4*)s; rB[p][1] = *(const float4*)(s + 4);
        }
    };
    auto storeTile = [&](int buf) {
#pragma unroll
        for (int p = 0; p < 2; p++) {
            int ch = p * 256 + t8, r = ch >> 2, c8 = (ch & 3) << 3;
            *(bf16x8*)&Smem[buf][grp][r][c8] = rA[p];
            bf16x8 t;
            t[0]=(bf16)rB[p][0].x; t[1]=(bf16)rB[p][0].y; t[2]=(bf16)rB[p][0].z; t[3]=(bf16)rB[p][0].w;
            t[4]=(bf16)rB[p][1].x; t[5]=(bf16)rB[p][1].y; t[6]=(bf16)rB[p][1].z; t[7]=(bf16)rB[p][1].w;
            *(bf16x8*)&Smem[buf][grp][128 + r][c8] = t;
        }
    };

    const int kbase = grp * 512;
    loadTile(kbase);
    storeTile(0);
    __syncthreads();
    for (int k = 0; k < 16; k++) {
        const bool more = k < 15;
        if (more) loadTile(kbase + ((k + 1) << 5));
        const int buf = k & 1;
        bf16x8 af[4], bfr[4];
#pragma unroll
        for (int i = 0; i < 4; i++)
            af[i] = *(const bf16x8*)&Smem[buf][grp][wm * 64 + i * 16 + l16][quad * 8];
#pragma unroll
        for (int j = 0; j < 4; j++) {
            int brow = (j < 2) ? (wn * 32 + j * 16) : (64 + wn * 32 + (j - 2) * 16);
            bfr[j] = *(const bf16x8*)&Smem[buf][grp][128 + brow + l16][quad * 8];
        }
#pragma unroll
        for (int i = 0; i < 4; i++)
#pragma unroll
            for (int j = 0; j < 4; j++)
                acc[i][j] = MFMA16(af[i], bfr[j], acc[i][j]);
        if (more) { storeTile(buf ^ 1); __syncthreads(); }
    }

    // --- combine group 1 -> group 0 via LDS (aRow*128 + bRow, 64 KB) ---
    __syncthreads();
    float* red = (float*)&Smem[0][0][0][0];
    if (grp == 1) {
#pragma unroll
        for (int i = 0; i < 4; i++)
#pragma unroll
            for (int j = 0; j < 4; j++) {
                int brow = ((j < 2) ? (wn * 32 + j * 16)
                                    : (64 + wn * 32 + (j - 2) * 16)) + l16;
#pragma unroll
                for (int r = 0; r < 4; r++)
                    red[(wm * 64 + i * 16 + quad * 4 + r) * 128 + brow] = acc[i][j][r];
            }
    }
    __syncthreads();
    if (grp != 0) return;
#pragma unroll
    for (int i = 0; i < 4; i++)
#pragma unroll
        for (int j = 0; j < 4; j++) {
            int brow = ((j < 2) ? (wn * 32 + j * 16)
                                : (64 + wn * 32 + (j - 2) * 16)) + l16;
#pragma unroll
            for (int r = 0; r < 4; r++)
                acc[i][j][r] += red[(wm * 64 + i * 16 + quad * 4 + r) * 128 + brow];
        }

#pragma unroll
    for (int i = 0; i < 4; i++) {
        int row0 = rowBase + wm * 64 + i * 16 + quad * 4;
#pragma unroll
        for (int jj = 0; jj < 2; jj++) {
            int col = cb * 64 + wn * 32 + jj * 16 + l16;
#pragma unroll
            for (int r = 0; r < 4; r++) {
                float u1 = acc[i][jj][r], u2 = acc[i][jj + 2][r];
                float g = u1 / (1.f + __expf(-u1));
                Out[(size_t)(row0 + r) * 2048 + col] = (bf16)(g * u2);
            }
        }
    }
}

// ---------------------------------------------------------------------------
__global__ __launch_bounds__(256) void rmsnorm_k(
    const float* __restrict__ X, const float* __restrict__ W,
    bf16* __restrict__ Out)
{
    const int row = blockIdx.x, tid = threadIdx.x;
    const float4 xv = *(const float4*)(X + (size_t)row * 1024 + tid * 4);
    float ss = xv.x * xv.x + xv.y * xv.y + xv.z * xv.z + xv.w * xv.w;
#pragma unroll
    for (int m = 1; m < 64; m <<= 1) ss += __shfl_xor(ss, m);
    __shared__ float red[4];
    if ((tid & 63) == 0) red[tid >> 6] = ss;
    __syncthreads();
    float tot = red[0] + red[1] + red[2] + red[3];
    float sc = rsqrtf(tot * (1.0f / 1024.0f) + 1e-5f);
    const float4 wv = *(const float4*)(W + tid * 4);
    bf16x4 o;
    o[0] = (bf16)(xv.x * sc * wv.x);
    o[1] = (bf16)(xv.y * sc * wv.y);
    o[2] = (bf16)(xv.z * sc * wv.z);
    o[3] = (bf16)(xv.w * sc * wv.w);
    *(bf16x4*)(Out + (size_t)row * 1024 + tid * 4) = o;
}

// ---------------------------------------------------------------------------
__global__ __launch_bounds__(256) void ropetab_k(float* __restrict__ tab)
{
    int i = blockIdx.x * 256 + threadIdx.x;  // 32768
    int s = i >> 5, j = i & 31;
    float f = (float)s * __expf(-(float)j * 0.2878231366242557f);  // ln(1e4)/32
    tab[i * 2]     = cosf(f);
    tab[i * 2 + 1] = sinf(f);
}

// ---------------------------------------------------------------------------
// l2norm + RoPE.  Scale 1/sqrt(A)=0.125 is folded into q here (exact in bf16:
// power-of-2 exponent shift) so attn_k's scores need no multiply and are
// bounded in [-0.125, 0.125] (|q.k| <= 1 since both unit-norm, RoPE is a
// rotation) -> max-free softmax in attn_k is numerically safe.
// ---------------------------------------------------------------------------
__global__ __launch_bounds__(256) void qkprep_k(
    bf16* __restrict__ qkv, const float* __restrict__ tab)
{
    int wid  = blockIdx.x * 4 + (threadIdx.x >> 6);
    int lane = threadIdx.x & 63;
    int s = wid & 1023, h = (wid >> 10) & 15, b = (wid >> 14) & 1, op = wid >> 15;
    bf16* addr = qkv + ((size_t)(b * 1024 + s)) * 3072 + op * 1024 + h * 64 + lane;
    float v = (float)*addr;
    float ss = v * v;
#pragma unroll
    for (int m = 1; m < 64; m <<= 1) ss += __shfl_xor(ss, m);
    v /= fmaxf(sqrtf(ss), 1e-5f);
    float2 cssn = ((const float2*)tab)[(s << 5) + (lane & 31)];
    float partner = __shfl_xor(v, 32);
    float o = (lane < 32) ? (v * cssn.x + partner * cssn.y)
                          : (v * cssn.x - partner * cssn.y);
    if (op == 0) o *= 0.125f;   // fold attention scale into q
    *addr = (bf16)o;
}

// ---------------------------------------------------------------------------
__global__ __launch_bounds__(256) void vtrans_k(
    const bf16* __restrict__ qkv, bf16* __restrict__ Vt)
{
    __shared__ __align__(16) bf16 Ls[64][72];
    const int st = blockIdx.x, h = blockIdx.y, b = blockIdx.z;
    const int tid = threadIdx.x;
#pragma unroll
    for (int p = 0; p < 2; p++) {
        int s = p * 32 + (tid >> 3), a0 = (tid & 7) << 3;
        *(bf16x8*)&Ls[s][a0] = *(const bf16x8*)(
            qkv + ((size_t)(b * 1024 + st * 64 + s)) * 3072 + 2048 + h * 64 + a0);
    }
    __syncthreads();
#pragma unroll
    for (int p = 0; p < 2; p++) {
        int a = p * 32 + (tid >> 3), s0 = (tid & 7) << 3;
        bf16x8 v;
#pragma unroll
        for (int j = 0; j < 8; j++) v[j] = Ls[s0 + j][a];
        *(bf16x8*)(Vt + (((size_t)((b * 16 + h) * 64 + a)) << 10) + st * 64 + s0) = v;
    }
}

// ---------------------------------------------------------------------------
// Flash attention with KV-SPLIT, 8 waves/block (512 threads), grid (16,16,2).
// Wave pair (w, w+4) owns q-tile g = {p, 31-p, 32+p, 63-p}[w]; lower wave
// processes key tiles [0, Th), upper wave [Th, T) where T = causal tile
// count and Th = ceil(T/2).  Max-free softmax (scores in [-0.125, 0.125],
// scale folded into q) makes O and l plain sums -> the two partials merge
// with a single add via LDS.  Halves the serial key chain and doubles
// resident waves (attn is latency-bound: MfmaUtil 3.9%, Occ 13.6%).
// ---------------------------------------------------------------------------
__global__ __launch_bounds__(512) void attn_k(
    const bf16* __restrict__ qkv, const bf16* __restrict__ Vt,
    const int* __restrict__ doc, bf16* __restrict__ attnb)
{
    const int p = blockIdx.x, h = blockIdx.y, b = blockIdx.z;
    const int tid = threadIdx.x, w8 = tid >> 6, lane = tid & 63;
    const int w = w8 & 3, half = w8 >> 2;
    const int quad = lane >> 4, l16 = lane & 15;
    __shared__ __align__(16) bf16 PsT[8][64][20];   // [wave][key][qrow+pad]
    __shared__ float cmb[4][64][20];                // [pair][lane][O16 + lp4]
    __shared__ int docL[128];
    if (tid < 128) docL[tid] = doc[b * 128 + tid];
    __syncthreads();

    const int g = (w == 0) ? p : (w == 1) ? 31 - p : (w == 2) ? 32 + p : 63 - p;
    const bf16* qp = qkv + ((size_t)(b * 1024 + g * 16 + l16)) * 3072 + h * 64 + quad * 8;
    const bf16x8 qf0 = *(const bf16x8*)qp;
    const bf16x8 qf1 = *(const bf16x8*)(qp + 32);
    const bf16* Kbase = qkv + ((size_t)(b * 1024)) * 3072 + 1024 + h * 64;
    const bf16* Vbase = Vt + (((size_t)((b * 16 + h) * 64)) << 10);

    const f32x4 z4 = {0.f, 0.f, 0.f, 0.f};
    f32x4 O[4] = {z4, z4, z4, z4};
    float lp[4] = {0.f, 0.f, 0.f, 0.f};   // per-lane partial denominators

    int bq[4], dq[4];
#pragma unroll
    for (int r = 0; r < 4; r++) {
        bq[r] = (g * 16 + quad * 4 + r) >> 3;
        dq[r] = docL[bq[r]];
    }

    bf16x8 kc[8], kn[8];   // K frags cur/next: [keygroup16 * 2 + half]
    auto loadK = [&](int kt, bf16x8* dst) {
        const bf16* kp = Kbase + (size_t)(kt * 64 + l16) * 3072 + quad * 8;
#pragma unroll
        for (int kg = 0; kg < 4; kg++) {
            dst[kg * 2]     = *(const bf16x8*)(kp + (size_t)kg * 16 * 3072);
            dst[kg * 2 + 1] = *(const bf16x8*)(kp + (size_t)kg * 16 * 3072 + 32);
        }
    };

    const int T   = (g + 4) >> 2;    // causal tile count: ceil(16(g+1)/64)
    const int Th  = (T + 1) >> 1;
    const int kt0 = half ? Th : 0;
    const int kt1 = half ? T  : Th;

    if (kt0 < kt1) {
        loadK(kt0, kc);
        for (int kt = kt0; kt < kt1; kt++) {
            const int k0 = kt * 64;
            // --- QK^T: 8 MFMAs into 4 score frags (16 keys each) ---
            f32x4 sf[4];
#pragma unroll
            for (int kg = 0; kg < 4; kg++) {
                sf[kg] = z4;
                sf[kg] = MFMA16(qf0, kc[kg * 2],     sf[kg]);
                sf[kg] = MFMA16(qf1, kc[kg * 2 + 1], sf[kg]);
            }
            // --- issue prefetches: V for THIS tile + K for NEXT tile ---
            bf16x8 vr[4][2];
#pragma unroll
            for (int t = 0; t < 4; t++)
#pragma unroll
                for (int c = 0; c < 2; c++)
                    vr[t][c] = *(const bf16x8*)(
                        Vbase + ((size_t)(t * 16 + l16) << 10) + k0 + c * 32 + quad * 8);
            if (kt + 1 < kt1) loadK(kt + 1, kn);

            // --- max-free masked softmax: p = ok ? exp(s) : 0 ---
            float pvv[4][4];   // pvv[kg][r]
#pragma unroll
            for (int kg = 0; kg < 4; kg++) {
                int kgi = k0 + kg * 16 + l16;
                int bk  = kgi >> 3;
                int dkv = docL[bk];
                bool kbit = (kgi & 7) < 4;
#pragma unroll
                for (int r = 0; r < 4; r++) {
                    bool ok = (bq[r] == bk) || ((bq[r] >= bk) && kbit && (dq[r] == dkv));
                    float pp = ok ? __expf(sf[kg][r]) : 0.f;
                    pvv[kg][r] = pp;
                    lp[r] += pp;
                }
            }
            // --- P -> LDS (C layout) -> A-frag (wave-private, in-order DS) ---
#pragma unroll
            for (int kg = 0; kg < 4; kg++) {
                bf16x4 t4;
#pragma unroll
                for (int r = 0; r < 4; r++) t4[r] = (bf16)pvv[kg][r];
                *(bf16x4*)&PsT[w8][kg * 16 + l16][quad * 4] = t4;
            }
            bf16x8 pa0, pa1;
#pragma unroll
            for (int j = 0; j < 8; j++) {
                pa0[j] = PsT[w8][quad * 8 + j][l16];
                pa1[j] = PsT[w8][32 + quad * 8 + j][l16];
            }
            // --- PV: 8 MFMAs, no rescale ---
#pragma unroll
            for (int t = 0; t < 4; t++) {
                O[t] = MFMA16(pa0, vr[t][0], O[t]);
                O[t] = MFMA16(pa1, vr[t][1], O[t]);
            }
            if (kt + 1 < kt1) {
#pragma unroll
                for (int i = 0; i < 8; i++) kc[i] = kn[i];
            }
        }
    }

    // --- merge upper-half partials into lower wave (plain adds) ---
    if (half) {
#pragma unroll
        for (int t = 0; t < 4; t++)
#pragma unroll
            for (int r = 0; r < 4; r++) cmb[w][lane][t * 4 + r] = O[t][r];
#pragma unroll
        for (int r = 0; r < 4; r++) cmb[w][lane][16 + r] = lp[r];
    }
    __syncthreads();
    if (half) return;
#pragma unroll
    for (int t = 0; t < 4; t++)
#pragma unroll
        for (int r = 0; r < 4; r++) O[t][r] += cmb[w][lane][t * 4 + r];
#pragma unroll
    for (int r = 0; r < 4; r++) lp[r] += cmb[w][lane][16 + r];

    // --- single final denominator reduce (16-lane groups) ---
#pragma unroll
    for (int r = 0; r < 4; r++) {
#pragma unroll
        for (int m = 1; m < 16; m <<= 1) lp[r] += __shfl_xor(lp[r], m);
    }

#pragma unroll
    for (int t = 0; t < 4; t++)
#pragma unroll
        for (int r = 0; r < 4; r++) {
            int qg = g * 16 + quad * 4 + r;
            float v = O[t][r] / fmaxf(lp[r], 1e-20f);
            attnb[((size_t)(b * 1024) + qg) * 1024 + h * 64 + t * 16 + l16] = (bf16)v;
        }
}

// ---------------------------------------------------------------------------
__global__ __launch_bounds__(256) void permute_k(
    const bf16* __restrict__ t1, bf16* __restrict__ t1p)
{
    int idx = blockIdx.x * 256 + threadIdx.x;  // 262144
    int u = idx & 255, m = u >> 6, v = u & 63;
    int orow = idx >> 8;
    int k = orow & 3, bc = orow >> 2;
    int b = bc >> 7, c = bc & 127;
    t1p[idx] = t1[((size_t)(b * 512 + c * 4 + m)) * 256 + k * 64 + v];
}

__global__ __launch_bounds__(256) void buildx_k(
    const float* __restrict__ x_input, const float* __restrict__ t2,
    const float* __restrict__ pos_emb, float* __restrict__ xres)
{
    int idx = blockIdx.x * 256 + threadIdx.x;  // 2M
    int d = idx & 1023, row = idx >> 10;
    int b = row >> 10, rr = row & 1023;
    int c = rr >> 3, e = rr & 7;
    float v;
    if (e < 4)
        v = x_input[((size_t)(b * 512 + c * 4 + e)) * 1024 + d];
    else
        v = t2[((size_t)(b * 512 + c * 4 + (e - 4))) * 1024 + d] +
            pos_emb[(e - 4) * 1024 + d];
    xres[idx] = v;
}

__global__ __launch_bounds__(256) void finalout_k(
    const float* __restrict__ xres, float* __restrict__ out)
{
    int idx = blockIdx.x * 256 + threadIdx.x;  // 1M
    int d = idx & 1023, t = idx >> 10;
    int kk = t & 3, bc = t >> 2;
    int b = bc >> 7, c = bc & 127;
    out[idx] = xres[((size_t)(b * 1024 + c * 8 + 4 + kk)) * 1024 + d];
}

// ---------------------------------------------------------------------------
// Workspace (32 MB): same liveness plan as before.
// ---------------------------------------------------------------------------
extern "C" void kernel_launch(void* const* d_in, const int* in_sizes, int n_in,
                              void* d_out, int out_size, void* d_ws, size_t ws_size,
                              hipStream_t stream)
{
    const float* x_input = (const float*)d_in[0];
    const int*   doc     = (const int*)d_in[1];
    const float* dec_w1  = (const float*)d_in[2];
    const float* dec_w2  = (const float*)d_in[3];
    const float* pos_emb = (const float*)d_in[4];
    const float* Wqkv    = (const float*)d_in[5];
    const float* Wo      = (const float*)d_in[6];
    const float* Wup     = (const float*)d_in[7];
    const float* Wdown   = (const float*)d_in[8];
    const float* anw     = (const float*)d_in[9];
    const float* fnw     = (const float*)d_in[10];
    float* out = (float*)d_out;

    char* w = (char*)d_ws;
    float* xres  = (float*)(w);                    // [0,8)
    bf16*  attnb = (bf16*)(w + (8u << 20));        // [8,12)
    bf16*  t1    = (bf16*)(w + (8u << 20));        // prologue only
    bf16*  t1p   = (bf16*)(w + (8u << 20) + (512u << 10));
    bf16*  Vt    = (bf16*)(w + (12u << 20));       // [12,16)
    bf16*  xn2   = (bf16*)(w + (12u << 20));       // aliases Vt
    bf16*  qkv   = (bf16*)(w + (16u << 20));       // [16,28)
    float* t2    = (float*)(w + (16u << 20));      // [16,20) prologue only
    float* x1res = (float*)(w + (16u << 20));      // [16,24) (qkv dead post-attn)
    bf16*  hg    = (bf16*)(w + (24u << 20));       // [24,32)
    bf16*  xn1   = (bf16*)(w + (28u << 20));       // [28,32)
    float* rtab  = out;                            // 256 KB scratch in d_out

    // ---- prologue ----
    ropetab_k<<<128, 256, 0, stream>>>(rtab);
    gemm_bt<0, 1, 1, 64, 64><<<dim3(4, 16), 256, 0, stream>>>(
        x_input, dec_w1, nullptr, t1, 256, 1024, 1024);
    permute_k<<<1024, 256, 0, stream>>>(t1, t1p);
    gemm_bt<2, 0, 1, 64, 64><<<dim3(16, 16), 256, 0, stream>>>(
        t1p, dec_w2, nullptr, t2, 1024, 256, 256);
    buildx_k<<<8192, 256, 0, stream>>>(x_input, t2, pos_emb, xres);

    // ---- 4 transformer layers ----
    for (int li = 0; li < 4; ++li) {
        rmsnorm_k<<<2048, 256, 0, stream>>>(xres, anw + li * 1024, xn1);
        gemm_bt<0, 0, 1, 128, 128><<<dim3(24, 16), 256, 0, stream>>>(
            xn1, Wqkv + (size_t)li * 3072 * 1024, nullptr, qkv, 3072, 1024, 1024);
        qkprep_k<<<16384, 256, 0, stream>>>(qkv, rtab);
        vtrans_k<<<dim3(16, 16, 2), 256, 0, stream>>>(qkv, Vt);
        attn_k<<<dim3(16, 16, 2), 512, 0, stream>>>(qkv, Vt, doc, attnb);
        gemm_bt<1, 0, 1, 64, 64, 2><<<dim3(16, 32), 512, 0, stream>>>(
            attnb, Wo + (size_t)li * 1024 * 1024, xres, x1res, 1024, 1024, 1024);
        rmsnorm_k<<<2048, 256, 0, stream>>>(x1res, fnw + li * 1024, xn2);
        gemm_up_swiglu<<<dim3(32, 16), 512, 0, stream>>>(
            xn2, Wup + (size_t)li * 4096 * 1024, hg);
        gemm_bt<1, 0, 1, 64, 64, 2><<<dim3(16, 32), 512, 0, stream>>>(
            hg, Wdown + (size_t)li * 1024 * 2048, x1res, xres, 1024, 2048, 2048);
    }

    finalout_k<<<4096, 256, 0, stream>>>(xres, out);
}

// Round 5
// 885.529 us; speedup vs baseline: 1.0187x; 1.0187x over previous
//
#include <hip/hip_runtime.h>
#include <hip/hip_bf16.h>

typedef __bf16 bf16;
typedef __bf16 bf16x8 __attribute__((ext_vector_type(8)));
typedef __bf16 bf16x4 __attribute__((ext_vector_type(4)));
typedef float  f32x4  __attribute__((ext_vector_type(4)));

#define MFMA16(a, b, c) __builtin_amdgcn_mfma_f32_16x16x32_bf16(a, b, c, 0, 0, 0)

// ---------------------------------------------------------------------------
// Pipelined GEMM: C[M,N] = A[M,K] * B[N,K]^T.  A row stride lda.
// Double-buffered LDS + register prefetch; one barrier per K-iter.
// AF32/BF32: operand f32 in global -> bf16 at LDS-store time.
// EPI 0: bf16 out.  EPI 1: f32 out = acc + Res.  EPI 2: f32 out.
// SK=2: in-block split-K.  512 threads; wave-group g handles K-half g with
// its own LDS buffers; partials combined via LDS (aliases As) at the end.
// ---------------------------------------------------------------------------
template <int EPI, int AF32, int BF32, int TM, int TN, int SK = 1>
__global__ __launch_bounds__(256 * SK) void gemm_bt(
    const void* __restrict__ Av, const void* __restrict__ Bv,
    const float* __restrict__ Res, void* __restrict__ Out,
    int Ntot, int Ktot, int lda)
{
    constexpr int PA = TM / 64, PB = TN / 64;
    constexpr int WN = (TN == 128) ? ((TM == 128) ? 2 : 4) : 2;
    constexpr int WM = 4 / WN;
    constexpr int I = TM / (WM * 16), J = TN / (WN * 16);
    __shared__ __align__(16) bf16 As[2][SK][TM][40];
    __shared__ __align__(16) bf16 Bs[2][SK][TN][40];
    static_assert(SK == 1 || sizeof(As) >= TM * TN * 4, "combine buffer fits in As");
    const int tid  = threadIdx.x;
    const int grp  = (SK > 1) ? (tid >> 8) : 0;
    const int t8   = tid & 255;
    const int wave = t8 >> 6, lane = tid & 63;
    const int quad = lane >> 4, l16 = lane & 15;
    const int wm = wave / WN, wn = wave % WN;
    const int rowW = wm * (TM / WM), colW = wn * (TN / WN);
    const int rowBase = blockIdx.y * TM, colBase = blockIdx.x * TN;

    f32x4 acc[I][J];
    const f32x4 z4 = {0.f, 0.f, 0.f, 0.f};
#pragma unroll
    for (int i = 0; i < I; i++)
#pragma unroll
        for (int j = 0; j < J; j++) acc[i][j] = z4;

    float4 rAf[PA][2]; bf16x8 rAb[PA];
    float4 rBf[PB][2]; bf16x8 rBb[PB];

    auto loadTile = [&](int kt) {   // kt: absolute K offset
#pragma unroll
        for (int p = 0; p < PA; p++) {
            int ch = p * 256 + t8, r = ch >> 2, c8 = (ch & 3) << 3;
            if (AF32) {
                const float* s = (const float*)Av + (size_t)(rowBase + r) * lda + kt + c8;
                rAf[p][0] = *(const float4*)s; rAf[p][1] = *(const float4*)(s + 4);
            } else {
                rAb[p] = *(const bf16x8*)((const bf16*)Av + (size_t)(rowBase + r) * lda + kt + c8);
            }
        }
#pragma unroll
        for (int p = 0; p < PB; p++) {
            int ch = p * 256 + t8, r = ch >> 2, c8 = (ch & 3) << 3;
            if (BF32) {
                const float* s = (const float*)Bv + (size_t)(colBase + r) * Ktot + kt + c8;
                rBf[p][0] = *(const float4*)s; rBf[p][1] = *(const float4*)(s + 4);
            } else {
                rBb[p] = *(const bf16x8*)((const bf16*)Bv + (size_t)(colBase + r) * Ktot + kt + c8);
            }
        }
    };
    auto storeTile = [&](int buf) {
#pragma unroll
        for (int p = 0; p < PA; p++) {
            int ch = p * 256 + t8, r = ch >> 2, c8 = (ch & 3) << 3;
            bf16x8 t;
            if (AF32) {
                t[0]=(bf16)rAf[p][0].x; t[1]=(bf16)rAf[p][0].y; t[2]=(bf16)rAf[p][0].z; t[3]=(bf16)rAf[p][0].w;
                t[4]=(bf16)rAf[p][1].x; t[5]=(bf16)rAf[p][1].y; t[6]=(bf16)rAf[p][1].z; t[7]=(bf16)rAf[p][1].w;
            } else t = rAb[p];
            *(bf16x8*)&As[buf][grp][r][c8] = t;
        }
#pragma unroll
        for (int p = 0; p < PB; p++) {
            int ch = p * 256 + t8, r = ch >> 2, c8 = (ch & 3) << 3;
            bf16x8 t;
            if (BF32) {
                t[0]=(bf16)rBf[p][0].x; t[1]=(bf16)rBf[p][0].y; t[2]=(bf16)rBf[p][0].z; t[3]=(bf16)rBf[p][0].w;
                t[4]=(bf16)rBf[p][1].x; t[5]=(bf16)rBf[p][1].y; t[6]=(bf16)rBf[p][1].z; t[7]=(bf16)rBf[p][1].w;
            } else t = rBb[p];
            *(bf16x8*)&Bs[buf][grp][r][c8] = t;
        }
    };

    const int Kgrp  = Ktot / SK;
    const int kbase = grp * Kgrp;
    loadTile(kbase);
    storeTile(0);
    __syncthreads();
    const int nk = Kgrp >> 5;
    for (int k = 0; k < nk; k++) {
        const bool more = (k + 1) < nk;
        if (more) loadTile(kbase + ((k + 1) << 5));
        const int buf = k & 1;
        bf16x8 af[I], bfr[J];
#pragma unroll
        for (int i = 0; i < I; i++)
            af[i] = *(const bf16x8*)&As[buf][grp][rowW + i * 16 + l16][quad * 8];
#pragma unroll
        for (int j = 0; j < J; j++)
            bfr[j] = *(const bf16x8*)&Bs[buf][grp][colW + j * 16 + l16][quad * 8];
#pragma unroll
        for (int i = 0; i < I; i++)
#pragma unroll
            for (int j = 0; j < J; j++)
                acc[i][j] = MFMA16(af[i], bfr[j], acc[i][j]);
        if (more) { storeTile(buf ^ 1); __syncthreads(); }
    }

    // --- SK=2: combine group 1's partial into group 0 via LDS ---
    if (SK == 2) {
        __syncthreads();                       // all main-loop LDS reads done
        float* red = (float*)&As[0][0][0][0];  // TM*TN*4 bytes, fits (assert)
        if (grp == 1) {
#pragma unroll
            for (int i = 0; i < I; i++)
#pragma unroll
                for (int j = 0; j < J; j++)
#pragma unroll
                    for (int r = 0; r < 4; r++)
                        red[(rowW + i * 16 + quad * 4 + r) * TN +
                            (colW + j * 16 + l16)] = acc[i][j][r];
        }
        __syncthreads();
        if (grp != 0) return;
#pragma unroll
        for (int i = 0; i < I; i++)
#pragma unroll
            for (int j = 0; j < J; j++)
#pragma unroll
                for (int r = 0; r < 4; r++)
                    acc[i][j][r] += red[(rowW + i * 16 + quad * 4 + r) * TN +
                                        (colW + j * 16 + l16)];
    }

    // C/D layout: row = quad*4 + r, col = l16 (verified m89/m91)
#pragma unroll
    for (int i = 0; i < I; i++) {
        int row0 = rowBase + rowW + i * 16 + quad * 4;
#pragma unroll
        for (int j = 0; j < J; j++) {
            int col = colBase + colW + j * 16 + l16;
#pragma unroll
            for (int r = 0; r < 4; r++) {
                size_t off = (size_t)(row0 + r) * Ntot + col;
                float v = acc[i][j][r];
                if (EPI == 0)      ((bf16*)Out)[off]  = (bf16)v;
                else if (EPI == 1) ((float*)Out)[off] = v + Res[off];
                else               ((float*)Out)[off] = v;
            }
        }
    }
}

// ---------------------------------------------------------------------------
// Fused Wup GEMM + SwiGLU, in-block split-K (SK=2): 512 threads.
// Wave-group grp handles K-half grp (16 iters instead of 32) with its own
// LDS double-buffer; partials combined via 64 KB LDS f32 buffer (aliases
// Smem).  128row x 64col hg tile per block.
// Smem rows: [0,128) = A tile, [128,256) = B tile.
// ---------------------------------------------------------------------------
__global__ __launch_bounds__(512) void gemm_up_swiglu(
    const bf16* __restrict__ A, const float* __restrict__ B,
    bf16* __restrict__ Out)
{
    __shared__ __align__(16) bf16 Smem[2][2][256][40];   // 80 KB
    const int tid  = threadIdx.x;
    const int grp  = tid >> 8, t8 = tid & 255;
    const int wave = t8 >> 6, lane = tid & 63;
    const int quad = lane >> 4, l16 = lane & 15;
    const int wm = wave >> 1, wn = wave & 1;
    const int rowBase = blockIdx.y * 128, cb = blockIdx.x;

    f32x4 acc[4][4];
    const f32x4 z4 = {0.f, 0.f, 0.f, 0.f};
#pragma unroll
    for (int i = 0; i < 4; i++)
#pragma unroll
        for (int j = 0; j < 4; j++) acc[i][j] = z4;

    bf16x8 rA[2]; float4 rB[2][2];
    auto loadTile = [&](int kt) {   // absolute K offset
#pragma unroll
        for (int p = 0; p < 2; p++) {
            int ch = p * 256 + t8, r = ch >> 2, c8 = (ch & 3) << 3;
            rA[p] = *(const bf16x8*)(A + (size_t)(rowBase + r) * 1024 + kt + c8);
            int brow = (r >> 6) * 2048 + cb * 64 + (r & 63);
            const float* s = B + (size_t)brow * 1024 + kt + c8;
            rB[p][0] = *(const float4*)s; rB[p][1] = *(const float4*)(s + 4);
        }
    };
    auto storeTile = [&](int buf) {
#pragma unroll
        for (int p = 0; p < 2; p++) {
            int ch = p * 256 + t8, r = ch >> 2, c8 = (ch & 3) << 3;
            *(bf16x8*)&Smem[buf][grp][r][c8] = rA[p];
            bf16x8 t;
            t[0]=(bf16)rB[p][0].x; t[1]=(bf16)rB[p][0].y; t[2]=(bf16)rB[p][0].z; t[3]=(bf16)rB[p][0].w;
            t[4]=(bf16)rB[p][1].x; t[5]=(bf16)rB[p][1].y; t[6]=(bf16)rB[p][1].z; t[7]=(bf16)rB[p][1].w;
            *(bf16x8*)&Smem[buf][grp][128 + r][c8] = t;
        }
    };

    const int kbase = grp * 512;
    loadTile(kbase);
    storeTile(0);
    __syncthreads();
    for (int k = 0; k < 16; k++) {
        const bool more = k < 15;
        if (more) loadTile(kbase + ((k + 1) << 5));
        const int buf = k & 1;
        bf16x8 af[4], bfr[4];
#pragma unroll
        for (int i = 0; i < 4; i++)
            af[i] = *(const bf16x8*)&Smem[buf][grp][wm * 64 + i * 16 + l16][quad * 8];
#pragma unroll
        for (int j = 0; j < 4; j++) {
            int brow = (j < 2) ? (wn * 32 + j * 16) : (64 + wn * 32 + (j - 2) * 16);
            bfr[j] = *(const bf16x8*)&Smem[buf][grp][128 + brow + l16][quad * 8];
        }
#pragma unroll
        for (int i = 0; i < 4; i++)
#pragma unroll
            for (int j = 0; j < 4; j++)
                acc[i][j] = MFMA16(af[i], bfr[j], acc[i][j]);
        if (more) { storeTile(buf ^ 1); __syncthreads(); }
    }

    // --- combine group 1 -> group 0 via LDS (aRow*128 + bRow, 64 KB) ---
    __syncthreads();
    float* red = (float*)&Smem[0][0][0][0];
    if (grp == 1) {
#pragma unroll
        for (int i = 0; i < 4; i++)
#pragma unroll
            for (int j = 0; j < 4; j++) {
                int brow = ((j < 2) ? (wn * 32 + j * 16)
                                    : (64 + wn * 32 + (j - 2) * 16)) + l16;
#pragma unroll
                for (int r = 0; r < 4; r++)
                    red[(wm * 64 + i * 16 + quad * 4 + r) * 128 + brow] = acc[i][j][r];
            }
    }
    __syncthreads();
    if (grp != 0) return;
#pragma unroll
    for (int i = 0; i < 4; i++)
#pragma unroll
        for (int j = 0; j < 4; j++) {
            int brow = ((j < 2) ? (wn * 32 + j * 16)
                                : (64 + wn * 32 + (j - 2) * 16)) + l16;
#pragma unroll
            for (int r = 0; r < 4; r++)
                acc[i][j][r] += red[(wm * 64 + i * 16 + quad * 4 + r) * 128 + brow];
        }

#pragma unroll
    for (int i = 0; i < 4; i++) {
        int row0 = rowBase + wm * 64 + i * 16 + quad * 4;
#pragma unroll
        for (int jj = 0; jj < 2; jj++) {
            int col = cb * 64 + wn * 32 + jj * 16 + l16;
#pragma unroll
            for (int r = 0; r < 4; r++) {
                float u1 = acc[i][jj][r], u2 = acc[i][jj + 2][r];
                float g = u1 / (1.f + __expf(-u1));
                Out[(size_t)(row0 + r) * 2048 + col] = (bf16)(g * u2);
            }
        }
    }
}

// ---------------------------------------------------------------------------
__global__ __launch_bounds__(256) void rmsnorm_k(
    const float* __restrict__ X, const float* __restrict__ W,
    bf16* __restrict__ Out)
{
    const int row = blockIdx.x, tid = threadIdx.x;
    const float4 xv = *(const float4*)(X + (size_t)row * 1024 + tid * 4);
    float ss = xv.x * xv.x + xv.y * xv.y + xv.z * xv.z + xv.w * xv.w;
#pragma unroll
    for (int m = 1; m < 64; m <<= 1) ss += __shfl_xor(ss, m);
    __shared__ float red[4];
    if ((tid & 63) == 0) red[tid >> 6] = ss;
    __syncthreads();
    float tot = red[0] + red[1] + red[2] + red[3];
    float sc = rsqrtf(tot * (1.0f / 1024.0f) + 1e-5f);
    const float4 wv = *(const float4*)(W + tid * 4);
    bf16x4 o;
    o[0] = (bf16)(xv.x * sc * wv.x);
    o[1] = (bf16)(xv.y * sc * wv.y);
    o[2] = (bf16)(xv.z * sc * wv.z);
    o[3] = (bf16)(xv.w * sc * wv.w);
    *(bf16x4*)(Out + (size_t)row * 1024 + tid * 4) = o;
}

// ---------------------------------------------------------------------------
__global__ __launch_bounds__(256) void ropetab_k(float* __restrict__ tab)
{
    int i = blockIdx.x * 256 + threadIdx.x;  // 32768
    int s = i >> 5, j = i & 31;
    float f = (float)s * __expf(-(float)j * 0.2878231366242557f);  // ln(1e4)/32
    tab[i * 2]     = cosf(f);
    tab[i * 2 + 1] = sinf(f);
}

// ---------------------------------------------------------------------------
// l2norm + RoPE.  Scale 1/sqrt(A)=0.125 is folded into q here (exact in bf16:
// power-of-2 exponent shift) so attn_k's scores need no multiply and are
// bounded in [-0.125, 0.125] (|q.k| <= 1 since both unit-norm, RoPE is a
// rotation) -> max-free softmax in attn_k is numerically safe.
// ---------------------------------------------------------------------------
__global__ __launch_bounds__(256) void qkprep_k(
    bf16* __restrict__ qkv, const float* __restrict__ tab)
{
    int wid  = blockIdx.x * 4 + (threadIdx.x >> 6);
    int lane = threadIdx.x & 63;
    int s = wid & 1023, h = (wid >> 10) & 15, b = (wid >> 14) & 1, op = wid >> 15;
    bf16* addr = qkv + ((size_t)(b * 1024 + s)) * 3072 + op * 1024 + h * 64 + lane;
    float v = (float)*addr;
    float ss = v * v;
#pragma unroll
    for (int m = 1; m < 64; m <<= 1) ss += __shfl_xor(ss, m);
    v /= fmaxf(sqrtf(ss), 1e-5f);
    float2 cssn = ((const float2*)tab)[(s << 5) + (lane & 31)];
    float partner = __shfl_xor(v, 32);
    float o = (lane < 32) ? (v * cssn.x + partner * cssn.y)
                          : (v * cssn.x - partner * cssn.y);
    if (op == 0) o *= 0.125f;   // fold attention scale into q
    *addr = (bf16)o;
}

// ---------------------------------------------------------------------------
__global__ __launch_bounds__(256) void vtrans_k(
    const bf16* __restrict__ qkv, bf16* __restrict__ Vt)
{
    __shared__ __align__(16) bf16 Ls[64][72];
    const int st = blockIdx.x, h = blockIdx.y, b = blockIdx.z;
    const int tid = threadIdx.x;
#pragma unroll
    for (int p = 0; p < 2; p++) {
        int s = p * 32 + (tid >> 3), a0 = (tid & 7) << 3;
        *(bf16x8*)&Ls[s][a0] = *(const bf16x8*)(
            qkv + ((size_t)(b * 1024 + st * 64 + s)) * 3072 + 2048 + h * 64 + a0);
    }
    __syncthreads();
#pragma unroll
    for (int p = 0; p < 2; p++) {
        int a = p * 32 + (tid >> 3), s0 = (tid & 7) << 3;
        bf16x8 v;
#pragma unroll
        for (int j = 0; j < 8; j++) v[j] = Ls[s0 + j][a];
        *(bf16x8*)(Vt + (((size_t)((b * 16 + h) * 64 + a)) << 10) + st * 64 + s0) = v;
    }
}

// ---------------------------------------------------------------------------
// Flash attention, block-cooperative LDS-staged K/V.  Grid (16,16,2),
// 4 waves/block (256 thr).  Wave w owns q-tile g = 4p + w (consecutive ->
// per-wave tile counts differ by <=1 and waves share the K/V prefix, so ONE
// staged tile serves all 4 waves).  Per 64-key tile, the whole block stages
// K (8 KB) and Vt (8 KB) into LDS with fully-coalesced 16B/lane loads
// (fixes the TA-divergence bottleneck: per-wave register loads hit 32
// scattered cachelines per instr).  Double-buffered, register-prefetched,
// one barrier/tile.  Fragments read as ds_read_b128 (72-pad -> free 2-way).
// MAX-FREE softmax (scores in [-0.125,0.125], scale folded into q).
// ---------------------------------------------------------------------------
__global__ __launch_bounds__(256) void attn_k(
    const bf16* __restrict__ qkv, const bf16* __restrict__ Vt,
    const int* __restrict__ doc, bf16* __restrict__ attnb)
{
    const int p = blockIdx.x, h = blockIdx.y, b = blockIdx.z;
    const int tid = threadIdx.x, w = tid >> 6, lane = tid & 63;
    const int quad = lane >> 4, l16 = lane & 15;
    __shared__ __align__(16) bf16 Ks[2][64][72];   // [buf][key][d]
    __shared__ __align__(16) bf16 Vs[2][64][72];   // [buf][d][key]
    __shared__ __align__(16) bf16 PsT[4][64][20];  // [wave][key][qrow+pad]
    __shared__ int docL[128];
    if (tid < 128) docL[tid] = doc[b * 128 + tid];

    const int g = 4 * p + w;              // wave's q-tile
    const int Tw   = (g + 4) >> 2;        // causal tiles for this wave
    const int maxT = (4 * p + 7) >> 2;    // block tile count (= p+1)

    const bf16* qp = qkv + ((size_t)(b * 1024 + g * 16 + l16)) * 3072 + h * 64 + quad * 8;
    const bf16x8 qf0 = *(const bf16x8*)qp;
    const bf16x8 qf1 = *(const bf16x8*)(qp + 32);
    const bf16* Kbase = qkv + ((size_t)(b * 1024)) * 3072 + 1024 + h * 64;
    const bf16* Vbase = Vt + (((size_t)((b * 16 + h) * 64)) << 10);

    const f32x4 z4 = {0.f, 0.f, 0.f, 0.f};
    f32x4 O[4] = {z4, z4, z4, z4};
    float lp[4] = {0.f, 0.f, 0.f, 0.f};   // per-lane partial denominators

    __syncthreads();                      // docL visible
    int bq[4], dq[4];
#pragma unroll
    for (int r = 0; r < 4; r++) {
        bq[r] = (g * 16 + quad * 4 + r) >> 3;
        dq[r] = docL[bq[r]];
    }

    // --- coalesced staging: chunk ch covers row ch>>3, bf16 cols (ch&7)*8 ---
    bf16x8 rK[2], rV[2];
    auto stageRegs = [&](int kt) {
#pragma unroll
        for (int c = 0; c < 2; c++) {
            int ch = c * 256 + tid, r = ch >> 3, c8 = (ch & 7) << 3;
            rK[c] = *(const bf16x8*)(Kbase + (size_t)(kt * 64 + r) * 3072 + c8);
            rV[c] = *(const bf16x8*)(Vbase + ((size_t)r << 10) + kt * 64 + c8);
        }
    };
    auto stageLDS = [&](int buf) {
#pragma unroll
        for (int c = 0; c < 2; c++) {
            int ch = c * 256 + tid, r = ch >> 3, c8 = (ch & 7) << 3;
            *(bf16x8*)&Ks[buf][r][c8] = rK[c];
            *(bf16x8*)&Vs[buf][r][c8] = rV[c];
        }
    };

    stageRegs(0);
    stageLDS(0);
    __syncthreads();
    for (int kt = 0; kt < maxT; kt++) {
        const bool more = (kt + 1) < maxT;
        if (more) stageRegs(kt + 1);
        const int buf = kt & 1;
        if (kt < Tw) {
            const int k0 = kt * 64;
            // --- QK^T: 8 MFMAs, B-frags from LDS (vector b128) ---
            f32x4 sf[4];
#pragma unroll
            for (int kg = 0; kg < 4; kg++) {
                const bf16x8 k0f = *(const bf16x8*)&Ks[buf][kg * 16 + l16][quad * 8];
                const bf16x8 k1f = *(const bf16x8*)&Ks[buf][kg * 16 + l16][32 + quad * 8];
                sf[kg] = z4;
                sf[kg] = MFMA16(qf0, k0f, sf[kg]);
                sf[kg] = MFMA16(qf1, k1f, sf[kg]);
            }
            // --- max-free masked softmax: p = ok ? exp(s) : 0 ---
            float pvv[4][4];   // pvv[kg][r]
#pragma unroll
            for (int kg = 0; kg < 4; kg++) {
                int kgi = k0 + kg * 16 + l16;
                int bk  = kgi >> 3;
                int dkv = docL[bk];
                bool kbit = (kgi & 7) < 4;
#pragma unroll
                for (int r = 0; r < 4; r++) {
                    bool ok = (bq[r] == bk) || ((bq[r] >= bk) && kbit && (dq[r] == dkv));
                    float pp = ok ? __expf(sf[kg][r]) : 0.f;
                    pvv[kg][r] = pp;
                    lp[r] += pp;
                }
            }
            // --- P -> LDS (C layout) -> A-frag (wave-private, in-order DS) ---
#pragma unroll
            for (int kg = 0; kg < 4; kg++) {
                bf16x4 t4;
#pragma unroll
                for (int r = 0; r < 4; r++) t4[r] = (bf16)pvv[kg][r];
                *(bf16x4*)&PsT[w][kg * 16 + l16][quad * 4] = t4;
            }
            bf16x8 pa0, pa1;
#pragma unroll
            for (int j = 0; j < 8; j++) {
                pa0[j] = PsT[w][quad * 8 + j][l16];
                pa1[j] = PsT[w][32 + quad * 8 + j][l16];
            }
            // --- PV: 8 MFMAs, B-frags from LDS (vector b128) ---
#pragma unroll
            for (int t = 0; t < 4; t++) {
                const bf16x8 v0f = *(const bf16x8*)&Vs[buf][t * 16 + l16][quad * 8];
                const bf16x8 v1f = *(const bf16x8*)&Vs[buf][t * 16 + l16][32 + quad * 8];
                O[t] = MFMA16(pa0, v0f, O[t]);
                O[t] = MFMA16(pa1, v1f, O[t]);
            }
        }
        if (more) stageLDS(buf ^ 1);
        __syncthreads();
    }

    // --- single final denominator reduce (16-lane groups) ---
#pragma unroll
    for (int r = 0; r < 4; r++) {
#pragma unroll
        for (int m = 1; m < 16; m <<= 1) lp[r] += __shfl_xor(lp[r], m);
    }

#pragma unroll
    for (int t = 0; t < 4; t++)
#pragma unroll
        for (int r = 0; r < 4; r++) {
            int qg = g * 16 + quad * 4 + r;
            float v = O[t][r] / fmaxf(lp[r], 1e-20f);
            attnb[((size_t)(b * 1024) + qg) * 1024 + h * 64 + t * 16 + l16] = (bf16)v;
        }
}

// ---------------------------------------------------------------------------
__global__ __launch_bounds__(256) void permute_k(
    const bf16* __restrict__ t1, bf16* __restrict__ t1p)
{
    int idx = blockIdx.x * 256 + threadIdx.x;  // 262144
    int u = idx & 255, m = u >> 6, v = u & 63;
    int orow = idx >> 8;
    int k = orow & 3, bc = orow >> 2;
    int b = bc >> 7, c = bc & 127;
    t1p[idx] = t1[((size_t)(b * 512 + c * 4 + m)) * 256 + k * 64 + v];
}

__global__ __launch_bounds__(256) void buildx_k(
    const float* __restrict__ x_input, const float* __restrict__ t2,
    const float* __restrict__ pos_emb, float* __restrict__ xres)
{
    int idx = blockIdx.x * 256 + threadIdx.x;  // 2M
    int d = idx & 1023, row = idx >> 10;
    int b = row >> 10, rr = row & 1023;
    int c = rr >> 3, e = rr & 7;
    float v;
    if (e < 4)
        v = x_input[((size_t)(b * 512 + c * 4 + e)) * 1024 + d];
    else
        v = t2[((size_t)(b * 512 + c * 4 + (e - 4))) * 1024 + d] +
            pos_emb[(e - 4) * 1024 + d];
    xres[idx] = v;
}

__global__ __launch_bounds__(256) void finalout_k(
    const float* __restrict__ xres, float* __restrict__ out)
{
    int idx = blockIdx.x * 256 + threadIdx.x;  // 1M
    int d = idx & 1023, t = idx >> 10;
    int kk = t & 3, bc = t >> 2;
    int b = bc >> 7, c = bc & 127;
    out[idx] = xres[((size_t)(b * 1024 + c * 8 + 4 + kk)) * 1024 + d];
}

// ---------------------------------------------------------------------------
// Workspace (32 MB): same liveness plan as before.
// ---------------------------------------------------------------------------
extern "C" void kernel_launch(void* const* d_in, const int* in_sizes, int n_in,
                              void* d_out, int out_size, void* d_ws, size_t ws_size,
                              hipStream_t stream)
{
    const float* x_input = (const float*)d_in[0];
    const int*   doc     = (const int*)d_in[1];
    const float* dec_w1  = (const float*)d_in[2];
    const float* dec_w2  = (const float*)d_in[3];
    const float* pos_emb = (const float*)d_in[4];
    const float* Wqkv    = (const float*)d_in[5];
    const float* Wo      = (const float*)d_in[6];
    const float* Wup     = (const float*)d_in[7];
    const float* Wdown   = (const float*)d_in[8];
    const float* anw     = (const float*)d_in[9];
    const float* fnw     = (const float*)d_in[10];
    float* out = (float*)d_out;

    char* w = (char*)d_ws;
    float* xres  = (float*)(w);                    // [0,8)
    bf16*  attnb = (bf16*)(w + (8u << 20));        // [8,12)
    bf16*  t1    = (bf16*)(w + (8u << 20));        // prologue only
    bf16*  t1p   = (bf16*)(w + (8u << 20) + (512u << 10));
    bf16*  Vt    = (bf16*)(w + (12u << 20));       // [12,16)
    bf16*  xn2   = (bf16*)(w + (12u << 20));       // aliases Vt
    bf16*  qkv   = (bf16*)(w + (16u << 20));       // [16,28)
    float* t2    = (float*)(w + (16u << 20));      // [16,20) prologue only
    float* x1res = (float*)(w + (16u << 20));      // [16,24) (qkv dead post-attn)
    bf16*  hg    = (bf16*)(w + (24u << 20));       // [24,32)
    bf16*  xn1   = (bf16*)(w + (28u << 20));       // [28,32)
    float* rtab  = out;                            // 256 KB scratch in d_out

    // ---- prologue ----
    ropetab_k<<<128, 256, 0, stream>>>(rtab);
    gemm_bt<0, 1, 1, 64, 64><<<dim3(4, 16), 256, 0, stream>>>(
        x_input, dec_w1, nullptr, t1, 256, 1024, 1024);
    permute_k<<<1024, 256, 0, stream>>>(t1, t1p);
    gemm_bt<2, 0, 1, 64, 64><<<dim3(16, 16), 256, 0, stream>>>(
        t1p, dec_w2, nullptr, t2, 1024, 256, 256);
    buildx_k<<<8192, 256, 0, stream>>>(x_input, t2, pos_emb, xres);

    // ---- 4 transformer layers ----
    for (int li = 0; li < 4; ++li) {
        rmsnorm_k<<<2048, 256, 0, stream>>>(xres, anw + li * 1024, xn1);
        gemm_bt<0, 0, 1, 128, 128><<<dim3(24, 16), 256, 0, stream>>>(
            xn1, Wqkv + (size_t)li * 3072 * 1024, nullptr, qkv, 3072, 1024, 1024);
        qkprep_k<<<16384, 256, 0, stream>>>(qkv, rtab);
        vtrans_k<<<dim3(16, 16, 2), 256, 0, stream>>>(qkv, Vt);
        attn_k<<<dim3(16, 16, 2), 256, 0, stream>>>(qkv, Vt, doc, attnb);
        gemm_bt<1, 0, 1, 64, 64, 2><<<dim3(16, 32), 512, 0, stream>>>(
            attnb, Wo + (size_t)li * 1024 * 1024, xres, x1res, 1024, 1024, 1024);
        rmsnorm_k<<<2048, 256, 0, stream>>>(x1res, fnw + li * 1024, xn2);
        gemm_up_swiglu<<<dim3(32, 16), 512, 0, stream>>>(
            xn2, Wup + (size_t)li * 4096 * 1024, hg);
        gemm_bt<1, 0, 1, 64, 64, 2><<<dim3(16, 32), 512, 0, stream>>>(
            hg, Wdown + (size_t)li * 1024 * 2048, x1res, xres, 1024, 2048, 2048);
    }

    finalout_k<<<4096, 256, 0, stream>>>(xres, out);
}